// Round 1
// baseline (4049.066 us; speedup 1.0000x reference)
//
#include <hip/hip_runtime.h>

#define NP 50000
#define NA 20000
#define EW 400000
#define EC 800000
#define ER 400000

// ---------------------------------------------------------------- prep
__global__ __launch_bounds__(256) void prep_k(
    const float* __restrict__ Wr0w, const float* __restrict__ Wr0c,
    const float* __restrict__ bl0w, const float* __restrict__ bl0c,
    const float* __restrict__ Wr1w, const float* __restrict__ Wr1c,
    const float* __restrict__ bl1w, const float* __restrict__ bl1c,
    float* __restrict__ Wr0wc, float* __restrict__ b0p,
    float* __restrict__ Wr1wc, float* __restrict__ b1p)
{
    int i = blockIdx.x * 256 + threadIdx.x;
    if (i < 128*128) Wr0wc[i] = Wr0w[i] + Wr0c[i];
    if (i < 128*40)  Wr1wc[i] = Wr1w[i] + Wr1c[i];
    if (i < 128)     b0p[i] = 0.5f*(bl0w[i] + bl0c[i]);
    if (i < 40)      b1p[i] = 0.5f*(bl1w[i] + bl1c[i]);
}

// ---------------------------------------------------------------- counts
__global__ __launch_bounds__(256) void count_k(const int* __restrict__ dst, int E,
                                               float* __restrict__ cnt)
{
    int i = blockIdx.x * 256 + threadIdx.x;
    if (i < E) atomicAdd(&cnt[dst[i]], 1.0f);
}

// ---------------------------------------------------------------- scatter-add (atomic)
// DQ = float4 groups per feature row (32 for D=128, 10 for D=40)
template<int DQ>
__global__ __launch_bounds__(256) void scatter_k(
    const float* __restrict__ X, const int* __restrict__ src, const int* __restrict__ dst,
    int E, float* __restrict__ AGG)
{
    int t = blockIdx.x * 256 + threadIdx.x;
    int e = t / DQ;
    int g = t - e * DQ;
    if (e >= E) return;
    int s = src[e];
    int d = dst[e];
    float4 v = reinterpret_cast<const float4*>(X + (size_t)s * (DQ*4))[g];
    float* outp = AGG + (size_t)d * (DQ*4) + (size_t)g*4;
    atomicAdd(outp+0, v.x);
    atomicAdd(outp+1, v.y);
    atomicAdd(outp+2, v.z);
    atomicAdd(outp+3, v.w);
}

// ---------------------------------------------------------------- GEMM K=128, N=128
// C[M,128] (+)= (A .* rowscale) @ B ; optional epilogue: C = relu(alpha*C + bias)
// rowscale = 1/max(cnt[row],1) when cnt != nullptr (folds mean normalization)
__global__ __launch_bounds__(256) void gemm128_k(
    const float* __restrict__ A, const float* __restrict__ cnt,
    const float* __restrict__ B, float* __restrict__ C, int M,
    int accumulate, int finalize, float alpha, const float* __restrict__ bias, int relu)
{
    __shared__ float As[64][128];   // 32 KB
    __shared__ float Bs[32][128];   // 16 KB
    const int tid  = threadIdx.x;
    const int row0 = blockIdx.x * 64;

    // load A tile (64 x 128): 2048 float4, 8 per thread
#pragma unroll
    for (int i = 0; i < 8; ++i) {
        int idx = tid + i*256;
        int r = idx >> 5, c4 = idx & 31;
        int row = row0 + r;
        float4 v = make_float4(0.f,0.f,0.f,0.f);
        if (row < M) {
            v = reinterpret_cast<const float4*>(A + (size_t)row*128)[c4];
            if (cnt) {
                float s = 1.0f / fmaxf(cnt[row], 1.0f);
                v.x *= s; v.y *= s; v.z *= s; v.w *= s;
            }
        }
        reinterpret_cast<float4*>(&As[r][0])[c4] = v;
    }

    float acc[8][4];
#pragma unroll
    for (int r = 0; r < 8; ++r)
#pragma unroll
        for (int c = 0; c < 4; ++c) acc[r][c] = 0.f;

    const int cg = tid & 31;   // cols cg*4 .. +3
    const int rg = tid >> 5;   // rows rg*8 .. +7

    for (int kc = 0; kc < 4; ++kc) {
        __syncthreads();
        // load B chunk (32 x 128): 1024 float4, 4 per thread
#pragma unroll
        for (int i = 0; i < 4; ++i) {
            int idx = tid + i*256;
            int r = idx >> 5, c4 = idx & 31;
            reinterpret_cast<float4*>(&Bs[r][0])[c4] =
                reinterpret_cast<const float4*>(B + (size_t)(kc*32 + r)*128)[c4];
        }
        __syncthreads();
#pragma unroll
        for (int k4 = 0; k4 < 8; ++k4) {
            float4 b0 = reinterpret_cast<const float4*>(&Bs[k4*4+0][0])[cg];
            float4 b1 = reinterpret_cast<const float4*>(&Bs[k4*4+1][0])[cg];
            float4 b2 = reinterpret_cast<const float4*>(&Bs[k4*4+2][0])[cg];
            float4 b3 = reinterpret_cast<const float4*>(&Bs[k4*4+3][0])[cg];
#pragma unroll
            for (int r = 0; r < 8; ++r) {
                float4 a = reinterpret_cast<const float4*>(&As[rg*8 + r][0])[kc*8 + k4];
                acc[r][0] += a.x*b0.x + a.y*b1.x + a.z*b2.x + a.w*b3.x;
                acc[r][1] += a.x*b0.y + a.y*b1.y + a.z*b2.y + a.w*b3.y;
                acc[r][2] += a.x*b0.z + a.y*b1.z + a.z*b2.z + a.w*b3.z;
                acc[r][3] += a.x*b0.w + a.y*b1.w + a.z*b2.w + a.w*b3.w;
            }
        }
    }

#pragma unroll
    for (int r = 0; r < 8; ++r) {
        int row = row0 + rg*8 + r;
        if (row >= M) continue;
        float4* cp = reinterpret_cast<float4*>(C + (size_t)row*128) + cg;
        float4 t;
        if (accumulate) {
            float4 prev = *cp;
            t.x = prev.x + acc[r][0]; t.y = prev.y + acc[r][1];
            t.z = prev.z + acc[r][2]; t.w = prev.w + acc[r][3];
        } else {
            t.x = acc[r][0]; t.y = acc[r][1]; t.z = acc[r][2]; t.w = acc[r][3];
        }
        if (finalize) {
            int cb = cg*4;
            t.x = alpha*t.x + bias[cb+0];
            t.y = alpha*t.y + bias[cb+1];
            t.z = alpha*t.z + bias[cb+2];
            t.w = alpha*t.w + bias[cb+3];
            if (relu) {
                t.x = fmaxf(t.x, 0.f); t.y = fmaxf(t.y, 0.f);
                t.z = fmaxf(t.z, 0.f); t.w = fmaxf(t.w, 0.f);
            }
        }
        *cp = t;
    }
}

// ---------------------------------------------------------------- GEMM K=128, N=40 (plain write)
__global__ __launch_bounds__(256) void gemm40_k(
    const float* __restrict__ A, const float* __restrict__ B, float* __restrict__ C, int M)
{
    __shared__ float Bs[128][40];   // 20 KB
    __shared__ float As[24][128];   // 12 KB
    const int tid  = threadIdx.x;
    const int row0 = blockIdx.x * 24;

    // load all of B (5120 f32 = 1280 float4), layout identical flat
#pragma unroll
    for (int i = 0; i < 5; ++i) {
        int idx = tid + i*256;
        reinterpret_cast<float4*>(&Bs[0][0])[idx] = reinterpret_cast<const float4*>(B)[idx];
    }
    // load A tile (24 x 128 = 768 float4)
#pragma unroll
    for (int i = 0; i < 3; ++i) {
        int idx = tid + i*256;
        int r = idx >> 5, c4 = idx & 31;
        int row = row0 + r;
        float4 v = make_float4(0.f,0.f,0.f,0.f);
        if (row < M) v = reinterpret_cast<const float4*>(A + (size_t)row*128)[c4];
        reinterpret_cast<float4*>(&As[r][0])[c4] = v;
    }
    __syncthreads();

    if (tid < 240) {
        int col  = tid % 40;
        int rsub = tid / 40;          // 0..5 -> rows rsub*4 .. +3
        float a0=0.f, a1=0.f, a2=0.f, a3=0.f;
        for (int k = 0; k < 128; ++k) {
            float b = Bs[k][col];
            a0 += As[rsub*4+0][k]*b;
            a1 += As[rsub*4+1][k]*b;
            a2 += As[rsub*4+2][k]*b;
            a3 += As[rsub*4+3][k]*b;
        }
        int rb = row0 + rsub*4;
        if (rb+0 < M) C[(size_t)(rb+0)*40 + col] = a0;
        if (rb+1 < M) C[(size_t)(rb+1)*40 + col] = a1;
        if (rb+2 < M) C[(size_t)(rb+2)*40 + col] = a2;
        if (rb+3 < M) C[(size_t)(rb+3)*40 + col] = a3;
    }
}

// ---------------------------------------------------------------- final combine
// out = 0.5*(agg1w/max(cw,1) + agg1c/max(cc,1) + out) + b1p
__global__ __launch_bounds__(256) void final_k(
    const float* __restrict__ agg1w, const float* __restrict__ agg1c,
    const float* __restrict__ cntw, const float* __restrict__ cntc,
    const float* __restrict__ b1p, float* __restrict__ out, int n)
{
    int i = blockIdx.x * 256 + threadIdx.x;
    if (i >= n) return;
    int r = i / 40, c = i - r*40;
    float rw = 1.0f / fmaxf(cntw[r], 1.0f);
    float rc = 1.0f / fmaxf(cntc[r], 1.0f);
    out[i] = 0.5f*(agg1w[i]*rw + agg1c[i]*rc + out[i]) + b1p[c];
}

// ---------------------------------------------------------------- launch
extern "C" void kernel_launch(void* const* d_in, const int* in_sizes, int n_in,
                              void* d_out, int out_size, void* d_ws, size_t ws_size,
                              hipStream_t stream)
{
    (void)in_sizes; (void)n_in; (void)out_size; (void)ws_size;

    const float* x_paper  = (const float*)d_in[0];
    const float* x_author = (const float*)d_in[1];
    const int*   ei_w     = (const int*)d_in[2];
    const int*   ei_c     = (const int*)d_in[3];
    const int*   ei_r     = (const int*)d_in[4];
    const float* Wl0w = (const float*)d_in[5];
    const float* bl0w = (const float*)d_in[6];
    const float* Wr0w = (const float*)d_in[7];
    const float* Wl0c = (const float*)d_in[8];
    const float* bl0c = (const float*)d_in[9];
    const float* Wr0c = (const float*)d_in[10];
    const float* Wl0r = (const float*)d_in[11];
    const float* bl0r = (const float*)d_in[12];
    const float* Wr0r = (const float*)d_in[13];
    const float* Wl1w = (const float*)d_in[14];
    const float* bl1w = (const float*)d_in[15];
    const float* Wr1w = (const float*)d_in[16];
    const float* Wl1c = (const float*)d_in[17];
    const float* bl1c = (const float*)d_in[18];
    const float* Wr1c = (const float*)d_in[19];
    // d_in[20..22] = Wl1_r / bl1_r / Wr1_r: dead (layer-1 author output unused)
    float* out = (float*)d_out;

    float* ws = (float*)d_ws;
    size_t off = 0;
    float* aggw  = ws + off; off += (size_t)NP*128;
    float* aggc  = ws + off; off += (size_t)NP*128;
    float* aggr  = ws + off; off += (size_t)NA*128;
    float* agg1w = ws + off; off += (size_t)NP*40;
    float* agg1c = ws + off; off += (size_t)NP*40;
    float* cntw  = ws + off; off += NP;
    float* cntc  = ws + off; off += NP;
    float* cntr  = ws + off; off += NA;
    size_t zeroFloats = off;                 // everything above must start at 0
    float* hp1   = ws + off; off += (size_t)NP*128;
    float* ha1   = ws + off; off += (size_t)NA*128;
    float* T1w   = ws + off; off += (size_t)NA*40;
    float* T1c   = ws + off; off += (size_t)NP*40;
    float* Wr0wc = ws + off; off += 128*128;
    float* b0p   = ws + off; off += 128;
    float* Wr1wc = ws + off; off += 128*40;
    float* b1p   = ws + off; off += 40;

    hipMemsetAsync(d_ws, 0, zeroFloats*sizeof(float), stream);

    prep_k<<<64, 256, 0, stream>>>(Wr0w, Wr0c, bl0w, bl0c, Wr1w, Wr1c, bl1w, bl1c,
                                   Wr0wc, b0p, Wr1wc, b1p);

    count_k<<<(EW+255)/256, 256, 0, stream>>>(ei_w + EW, EW, cntw);
    count_k<<<(EC+255)/256, 256, 0, stream>>>(ei_c + EC, EC, cntc);
    count_k<<<(ER+255)/256, 256, 0, stream>>>(ei_r + ER, ER, cntr);

    // layer 0: aggregate raw features (D=128)
    scatter_k<32><<<(size_t)EW*32/256, 256, 0, stream>>>(x_author, ei_w, ei_w+EW, EW, aggw);
    scatter_k<32><<<(size_t)EC*32/256, 256, 0, stream>>>(x_paper,  ei_c, ei_c+EC, EC, aggc);
    scatter_k<32><<<(size_t)ER*32/256, 256, 0, stream>>>(x_paper,  ei_r, ei_r+ER, ER, aggr);

    // hp1 = relu(0.5*(x_p@(Wr0w+Wr0c) + mean_w@Wl0w + mean_c@Wl0c) + 0.5*(bl0w+bl0c))
    gemm128_k<<<(NP+63)/64, 256, 0, stream>>>(x_paper, nullptr, Wr0wc, hp1, NP, 0,0,1.f,nullptr,0);
    gemm128_k<<<(NP+63)/64, 256, 0, stream>>>(aggw,    cntw,    Wl0w,  hp1, NP, 1,0,1.f,nullptr,0);
    gemm128_k<<<(NP+63)/64, 256, 0, stream>>>(aggc,    cntc,    Wl0c,  hp1, NP, 1,1,0.5f,b0p,1);
    // ha1 = relu(x_a@Wr0r + mean_r@Wl0r + bl0r)
    gemm128_k<<<(NA+63)/64, 256, 0, stream>>>(x_author, nullptr, Wr0r, ha1, NA, 0,0,1.f,nullptr,0);
    gemm128_k<<<(NA+63)/64, 256, 0, stream>>>(aggr,     cntr,    Wl0r, ha1, NA, 1,1,1.0f,bl0r,1);

    // layer 1: transform first (40 dims), then scatter
    gemm40_k<<<(NA+23)/24, 256, 0, stream>>>(ha1, Wl1w,  T1w, NA);
    gemm40_k<<<(NP+23)/24, 256, 0, stream>>>(hp1, Wl1c,  T1c, NP);
    gemm40_k<<<(NP+23)/24, 256, 0, stream>>>(hp1, Wr1wc, out, NP);   // root part -> d_out

    scatter_k<10><<<((size_t)EW*10+255)/256, 256, 0, stream>>>(T1w, ei_w, ei_w+EW, EW, agg1w);
    scatter_k<10><<<((size_t)EC*10+255)/256, 256, 0, stream>>>(T1c, ei_c, ei_c+EC, EC, agg1c);

    final_k<<<(NP*40+255)/256, 256, 0, stream>>>(agg1w, agg1c, cntw, cntc, b1p, out, NP*40);
}

// Round 4
// 1050.624 us; speedup vs baseline: 3.8540x; 3.8540x over previous
//
#include <hip/hip_runtime.h>

#define NP 50000
#define NA 20000
#define EW 400000
#define EC 800000
#define ER 400000

// ---------------------------------------------------------------- prep
__global__ __launch_bounds__(256) void prep_k(
    const float* __restrict__ Wr0w, const float* __restrict__ Wr0c,
    const float* __restrict__ bl0w, const float* __restrict__ bl0c,
    const float* __restrict__ Wr1w, const float* __restrict__ Wr1c,
    const float* __restrict__ bl1w, const float* __restrict__ bl1c,
    float* __restrict__ Wr0wc, float* __restrict__ b0p,
    float* __restrict__ Wr1wc, float* __restrict__ b1p)
{
    int i = blockIdx.x * 256 + threadIdx.x;
    if (i < 128*128) Wr0wc[i] = Wr0w[i] + Wr0c[i];
    if (i < 128*40)  Wr1wc[i] = Wr1w[i] + Wr1c[i];
    if (i < 128)     b0p[i] = 0.5f*(bl0w[i] + bl0c[i]);
    if (i < 40)      b1p[i] = 0.5f*(bl1w[i] + bl1c[i]);
}

// ---------------------------------------------------------------- degree histogram
__global__ __launch_bounds__(256) void count_k(const int* __restrict__ dst, int E,
                                               int* __restrict__ cnt)
{
    int i = blockIdx.x * 256 + threadIdx.x;
    if (i < E) atomicAdd(&cnt[dst[i]], 1);
}

// ---------------------------------------------------------------- 1-block exclusive scan
// off[0..n-1] = exclusive scan of cnt, off[n] = total
__global__ __launch_bounds__(1024) void scan_k(const int* __restrict__ cnt, int n,
                                               int* __restrict__ off)
{
    __shared__ int sa[1024], sb[1024];
    __shared__ int carry_s;
    const int tid = threadIdx.x;
    if (tid == 0) carry_s = 0;
    __syncthreads();
    const int nchunk = (n + 1023) / 1024;
    for (int c = 0; c < nchunk; ++c) {
        int i = c*1024 + tid;
        int v = (i < n) ? cnt[i] : 0;
        sa[tid] = v;
        __syncthreads();
        int* s = sa; int* d = sb;
        for (int sh = 1; sh < 1024; sh <<= 1) {
            int t = s[tid] + ((tid >= sh) ? s[tid - sh] : 0);
            d[tid] = t;
            __syncthreads();
            int* tmp = s; s = d; d = tmp;
        }
        int inc = s[tid];                // inclusive scan of this chunk
        int carry = carry_s;
        if (i < n) off[i] = carry + inc - v;
        __syncthreads();
        if (tid == 1023) carry_s = carry + inc;
        __syncthreads();
    }
    if (tid == 0) off[n] = carry_s;
}

// ---------------------------------------------------------------- adjacency fill
// consumes cnt as a countdown cursor (cnt becomes 0 after this)
__global__ __launch_bounds__(256) void fill_k(
    const int* __restrict__ src, const int* __restrict__ dst, int E,
    const int* __restrict__ off, int* __restrict__ cnt, int* __restrict__ adj)
{
    int i = blockIdx.x * 256 + threadIdx.x;
    if (i >= E) return;
    int d = dst[i];
    int p = atomicSub(&cnt[d], 1) - 1;
    adj[off[d] + p] = src[i];
}

// ---------------------------------------------------------------- gather-mean, D=128
// one wave per dst node; lane holds float2; mean folded in (scale by 1/max(deg,1))
__global__ __launch_bounds__(256) void gather128_k(
    const float* __restrict__ X, const int* __restrict__ off, const int* __restrict__ adj,
    float* __restrict__ AGG, int n_dst)
{
    int w    = blockIdx.x * 4 + (threadIdx.x >> 6);
    int lane = threadIdx.x & 63;
    if (w >= n_dst) return;
    int b = off[w], e = off[w+1];
    float2 acc = make_float2(0.f, 0.f);
    for (int j0 = b; j0 < e; j0 += 64) {
        int sl = (j0 + lane < e) ? adj[j0 + lane] : 0;
        int m  = min(64, e - j0);
        for (int k = 0; k < m; ++k) {
            int s = __shfl(sl, k, 64);
            float2 v = reinterpret_cast<const float2*>(X + (size_t)s * 128)[lane];
            acc.x += v.x; acc.y += v.y;
        }
    }
    float sc = 1.0f / fmaxf((float)(e - b), 1.0f);
    reinterpret_cast<float2*>(AGG + (size_t)w * 128)[lane] = make_float2(acc.x*sc, acc.y*sc);
}

// ---------------------------------------------------------------- gather-mean, D=40
__global__ __launch_bounds__(256) void gather40_k(
    const float* __restrict__ X, const int* __restrict__ off, const int* __restrict__ adj,
    float* __restrict__ AGG, int n_dst)
{
    int w    = blockIdx.x * 4 + (threadIdx.x >> 6);
    int lane = threadIdx.x & 63;
    if (w >= n_dst) return;
    int b = off[w], e = off[w+1];
    float acc = 0.f;
    const bool act = lane < 40;
    for (int j0 = b; j0 < e; j0 += 64) {
        int sl = (j0 + lane < e) ? adj[j0 + lane] : 0;
        int m  = min(64, e - j0);
        for (int k = 0; k < m; ++k) {
            int s = __shfl(sl, k, 64);
            if (act) acc += X[(size_t)s * 40 + lane];
        }
    }
    if (act) {
        float sc = 1.0f / fmaxf((float)(e - b), 1.0f);
        AGG[(size_t)w * 40 + lane] = acc * sc;
    }
}

// ---------------------------------------------------------------- GEMM K=128, N=128
// C[M,128] (+)= A @ B ; optional epilogue: C = relu(alpha*C + bias)
__global__ __launch_bounds__(256) void gemm128_k(
    const float* __restrict__ A, const float* __restrict__ B, float* __restrict__ C, int M,
    int accumulate, int finalize, float alpha, const float* __restrict__ bias, int relu)
{
    __shared__ float As[64][128];   // 32 KB
    __shared__ float Bs[32][128];   // 16 KB
    const int tid  = threadIdx.x;
    const int row0 = blockIdx.x * 64;

#pragma unroll
    for (int i = 0; i < 8; ++i) {
        int idx = tid + i*256;
        int r = idx >> 5, c4 = idx & 31;
        int row = row0 + r;
        float4 v = make_float4(0.f,0.f,0.f,0.f);
        if (row < M) v = reinterpret_cast<const float4*>(A + (size_t)row*128)[c4];
        reinterpret_cast<float4*>(&As[r][0])[c4] = v;
    }

    float acc[8][4];
#pragma unroll
    for (int r = 0; r < 8; ++r)
#pragma unroll
        for (int c = 0; c < 4; ++c) acc[r][c] = 0.f;

    const int cg = tid & 31;   // cols cg*4 .. +3
    const int rg = tid >> 5;   // rows rg*8 .. +7

    for (int kc = 0; kc < 4; ++kc) {
        __syncthreads();
#pragma unroll
        for (int i = 0; i < 4; ++i) {
            int idx = tid + i*256;
            int r = idx >> 5, c4 = idx & 31;
            reinterpret_cast<float4*>(&Bs[r][0])[c4] =
                reinterpret_cast<const float4*>(B + (size_t)(kc*32 + r)*128)[c4];
        }
        __syncthreads();
#pragma unroll
        for (int k4 = 0; k4 < 8; ++k4) {
            float4 b0 = reinterpret_cast<const float4*>(&Bs[k4*4+0][0])[cg];
            float4 b1 = reinterpret_cast<const float4*>(&Bs[k4*4+1][0])[cg];
            float4 b2 = reinterpret_cast<const float4*>(&Bs[k4*4+2][0])[cg];
            float4 b3 = reinterpret_cast<const float4*>(&Bs[k4*4+3][0])[cg];
#pragma unroll
            for (int r = 0; r < 8; ++r) {
                float4 a = reinterpret_cast<const float4*>(&As[rg*8 + r][0])[kc*8 + k4];
                acc[r][0] += a.x*b0.x + a.y*b1.x + a.z*b2.x + a.w*b3.x;
                acc[r][1] += a.x*b0.y + a.y*b1.y + a.z*b2.y + a.w*b3.y;
                acc[r][2] += a.x*b0.z + a.y*b1.z + a.z*b2.z + a.w*b3.z;
                acc[r][3] += a.x*b0.w + a.y*b1.w + a.z*b2.w + a.w*b3.w;
            }
        }
    }

#pragma unroll
    for (int r = 0; r < 8; ++r) {
        int row = row0 + rg*8 + r;
        if (row >= M) continue;
        float4* cp = reinterpret_cast<float4*>(C + (size_t)row*128) + cg;
        float4 t;
        if (accumulate) {
            float4 prev = *cp;
            t.x = prev.x + acc[r][0]; t.y = prev.y + acc[r][1];
            t.z = prev.z + acc[r][2]; t.w = prev.w + acc[r][3];
        } else {
            t.x = acc[r][0]; t.y = acc[r][1]; t.z = acc[r][2]; t.w = acc[r][3];
        }
        if (finalize) {
            int cb = cg*4;
            t.x = alpha*t.x + bias[cb+0];
            t.y = alpha*t.y + bias[cb+1];
            t.z = alpha*t.z + bias[cb+2];
            t.w = alpha*t.w + bias[cb+3];
            if (relu) {
                t.x = fmaxf(t.x, 0.f); t.y = fmaxf(t.y, 0.f);
                t.z = fmaxf(t.z, 0.f); t.w = fmaxf(t.w, 0.f);
            }
        }
        *cp = t;
    }
}

// ---------------------------------------------------------------- GEMM K=128, N=40
__global__ __launch_bounds__(256) void gemm40_k(
    const float* __restrict__ A, const float* __restrict__ B, float* __restrict__ C, int M)
{
    __shared__ float Bs[128][40];   // 20 KB
    __shared__ float As[24][128];   // 12 KB
    const int tid  = threadIdx.x;
    const int row0 = blockIdx.x * 24;

#pragma unroll
    for (int i = 0; i < 5; ++i) {
        int idx = tid + i*256;
        reinterpret_cast<float4*>(&Bs[0][0])[idx] = reinterpret_cast<const float4*>(B)[idx];
    }
#pragma unroll
    for (int i = 0; i < 3; ++i) {
        int idx = tid + i*256;
        int r = idx >> 5, c4 = idx & 31;
        int row = row0 + r;
        float4 v = make_float4(0.f,0.f,0.f,0.f);
        if (row < M) v = reinterpret_cast<const float4*>(A + (size_t)row*128)[c4];
        reinterpret_cast<float4*>(&As[r][0])[c4] = v;
    }
    __syncthreads();

    if (tid < 240) {
        int col  = tid % 40;
        int rsub = tid / 40;
        float a0=0.f, a1=0.f, a2=0.f, a3=0.f;
        for (int k = 0; k < 128; ++k) {
            float b = Bs[k][col];
            a0 += As[rsub*4+0][k]*b;
            a1 += As[rsub*4+1][k]*b;
            a2 += As[rsub*4+2][k]*b;
            a3 += As[rsub*4+3][k]*b;
        }
        int rb = row0 + rsub*4;
        if (rb+0 < M) C[(size_t)(rb+0)*40 + col] = a0;
        if (rb+1 < M) C[(size_t)(rb+1)*40 + col] = a1;
        if (rb+2 < M) C[(size_t)(rb+2)*40 + col] = a2;
        if (rb+3 < M) C[(size_t)(rb+3)*40 + col] = a3;
    }
}

// ---------------------------------------------------------------- final combine
// out = 0.5*(agg1w + agg1c + out) + b1p   (means already folded in gathers)
__global__ __launch_bounds__(256) void final_k(
    const float* __restrict__ agg1w, const float* __restrict__ agg1c,
    const float* __restrict__ b1p, float* __restrict__ out, int n)
{
    int i = blockIdx.x * 256 + threadIdx.x;
    if (i >= n) return;
    int c = i % 40;
    out[i] = 0.5f*(agg1w[i] + agg1c[i] + out[i]) + b1p[c];
}

// ---------------------------------------------------------------- launch
extern "C" void kernel_launch(void* const* d_in, const int* in_sizes, int n_in,
                              void* d_out, int out_size, void* d_ws, size_t ws_size,
                              hipStream_t stream)
{
    (void)in_sizes; (void)n_in; (void)out_size; (void)ws_size;

    const float* x_paper  = (const float*)d_in[0];
    const float* x_author = (const float*)d_in[1];
    const int*   ei_w     = (const int*)d_in[2];
    const int*   ei_c     = (const int*)d_in[3];
    const int*   ei_r     = (const int*)d_in[4];
    const float* Wl0w = (const float*)d_in[5];
    const float* bl0w = (const float*)d_in[6];
    const float* Wr0w = (const float*)d_in[7];
    const float* Wl0c = (const float*)d_in[8];
    const float* bl0c = (const float*)d_in[9];
    const float* Wr0c = (const float*)d_in[10];
    const float* Wl0r = (const float*)d_in[11];
    const float* bl0r = (const float*)d_in[12];
    const float* Wr0r = (const float*)d_in[13];
    const float* Wl1w = (const float*)d_in[14];
    const float* bl1w = (const float*)d_in[15];
    const float* Wr1w = (const float*)d_in[16];
    const float* Wl1c = (const float*)d_in[17];
    const float* bl1c = (const float*)d_in[18];
    const float* Wr1c = (const float*)d_in[19];
    // d_in[20..22] = Wl1_r / bl1_r / Wr1_r: dead (layer-1 author output unused)
    float* out = (float*)d_out;

    float* ws = (float*)d_ws;
    size_t o = 0;
    int* cntw = (int*)(ws + o); o += NP;
    int* cntc = (int*)(ws + o); o += NP;
    int* cntr = (int*)(ws + o); o += NA;
    const size_t zeroInts = o;               // memset region (cnt/cursor)
    int* offw = (int*)(ws + o); o += NP + 1;
    int* offc = (int*)(ws + o); o += NP + 1;
    int* offr = (int*)(ws + o); o += NA + 1;
    o = (o + 3) & ~(size_t)3;                // 16B-align float region
    int* adjw = (int*)(ws + o); o += EW;
    int* adjc = (int*)(ws + o); o += EC;
    int* adjr = (int*)(ws + o); o += ER;
    float* aggw = ws + o; o += (size_t)NP*128;
    float* aggc = ws + o; o += (size_t)NP*128;
    float* aggr = ws + o; o += (size_t)NA*128;
    float* hp1  = ws + o; o += (size_t)NP*128;
    float* ha1  = ws + o; o += (size_t)NA*128;
    float* Wr0wc = ws + o; o += 128*128;
    float* b0p   = ws + o; o += 128;
    float* Wr1wc = ws + o; o += 128*40;
    float* b1p   = ws + o; o += 40;
    // aliases (aggw/aggc free after layer-0 GEMMs)
    float* T1w   = aggw;                 // NA*40
    float* T1c   = aggw + (size_t)NA*40; // NP*40  (2.8M <= NP*128)
    float* agg1w = aggc;                 // NP*40
    float* agg1c = aggc + (size_t)NP*40; // NP*40  (4.0M <= NP*128)

    hipMemsetAsync(d_ws, 0, zeroInts * sizeof(int), stream);

    prep_k<<<64, 256, 0, stream>>>(Wr0w, Wr0c, bl0w, bl0c, Wr1w, Wr1c, bl1w, bl1c,
                                   Wr0wc, b0p, Wr1wc, b1p);

    // CSR build (per call; ws is re-poisoned between calls)
    count_k<<<(EW+255)/256, 256, 0, stream>>>(ei_w + EW, EW, cntw);
    count_k<<<(EC+255)/256, 256, 0, stream>>>(ei_c + EC, EC, cntc);
    count_k<<<(ER+255)/256, 256, 0, stream>>>(ei_r + ER, ER, cntr);
    scan_k<<<1, 1024, 0, stream>>>(cntw, NP, offw);
    scan_k<<<1, 1024, 0, stream>>>(cntc, NP, offc);
    scan_k<<<1, 1024, 0, stream>>>(cntr, NA, offr);
    fill_k<<<(EW+255)/256, 256, 0, stream>>>(ei_w, ei_w + EW, EW, offw, cntw, adjw);
    fill_k<<<(EC+255)/256, 256, 0, stream>>>(ei_c, ei_c + EC, EC, offc, cntc, adjc);
    fill_k<<<(ER+255)/256, 256, 0, stream>>>(ei_r, ei_r + ER, ER, offr, cntr, adjr);

    // layer 0: gather-mean of raw features (D=128), mean folded in
    gather128_k<<<(NP+3)/4, 256, 0, stream>>>(x_author, offw, adjw, aggw, NP);
    gather128_k<<<(NP+3)/4, 256, 0, stream>>>(x_paper,  offc, adjc, aggc, NP);
    gather128_k<<<(NA+3)/4, 256, 0, stream>>>(x_paper,  offr, adjr, aggr, NA);

    // hp1 = relu(0.5*(x_p@(Wr0w+Wr0c) + mean_w@Wl0w + mean_c@Wl0c) + 0.5*(bl0w+bl0c))
    gemm128_k<<<(NP+63)/64, 256, 0, stream>>>(x_paper, Wr0wc, hp1, NP, 0,0,1.f,nullptr,0);
    gemm128_k<<<(NP+63)/64, 256, 0, stream>>>(aggw,    Wl0w,  hp1, NP, 1,0,1.f,nullptr,0);
    gemm128_k<<<(NP+63)/64, 256, 0, stream>>>(aggc,    Wl0c,  hp1, NP, 1,1,0.5f,b0p,1);
    // ha1 = relu(x_a@Wr0r + mean_r@Wl0r + bl0r)
    gemm128_k<<<(NA+63)/64, 256, 0, stream>>>(x_author, Wr0r, ha1, NA, 0,0,1.f,nullptr,0);
    gemm128_k<<<(NA+63)/64, 256, 0, stream>>>(aggr,     Wl0r, ha1, NA, 1,1,1.0f,bl0r,1);

    // layer 1: transform first (40 dims), then gather
    gemm40_k<<<(NA+23)/24, 256, 0, stream>>>(ha1, Wl1w,  T1w, NA);
    gemm40_k<<<(NP+23)/24, 256, 0, stream>>>(hp1, Wl1c,  T1c, NP);
    gemm40_k<<<(NP+23)/24, 256, 0, stream>>>(hp1, Wr1wc, out, NP);   // root part -> d_out

    gather40_k<<<(NP+3)/4, 256, 0, stream>>>(T1w, offw, adjw, agg1w, NP);
    gather40_k<<<(NP+3)/4, 256, 0, stream>>>(T1c, offc, adjc, agg1c, NP);

    final_k<<<(NP*40+255)/256, 256, 0, stream>>>(agg1w, agg1c, b1p, out, NP*40);
}

// Round 5
// 721.054 us; speedup vs baseline: 5.6155x; 1.4571x over previous
//
#include <hip/hip_runtime.h>

#define NP 50000
#define NA 20000
#define EW 400000
#define EC 800000
#define ER 400000

// ---------------------------------------------------------------- prep
__global__ __launch_bounds__(256) void prep_k(
    const float* __restrict__ Wr0w, const float* __restrict__ Wr0c,
    const float* __restrict__ bl0w, const float* __restrict__ bl0c,
    const float* __restrict__ Wr1w, const float* __restrict__ Wr1c,
    const float* __restrict__ bl1w, const float* __restrict__ bl1c,
    float* __restrict__ Wr0wc, float* __restrict__ b0p,
    float* __restrict__ Wr1wc, float* __restrict__ b1p)
{
    int i = blockIdx.x * 256 + threadIdx.x;
    if (i < 128*128) Wr0wc[i] = Wr0w[i] + Wr0c[i];
    if (i < 128*40)  Wr1wc[i] = Wr1w[i] + Wr1c[i];
    if (i < 128)     b0p[i] = 0.5f*(bl0w[i] + bl0c[i]);
    if (i < 40)      b1p[i] = 0.5f*(bl1w[i] + bl1c[i]);
}

// ---------------------------------------------------------------- degree histograms (all 3 relations)
__global__ __launch_bounds__(256) void count_all_k(
    const int* __restrict__ ei_w, const int* __restrict__ ei_c, const int* __restrict__ ei_r,
    int* __restrict__ cntw, int* __restrict__ cntc, int* __restrict__ cntr)
{
    int i = blockIdx.x * 256 + threadIdx.x;
    if (i < EW)              atomicAdd(&cntw[ei_w[EW + i]], 1);
    else if (i < EW+EC)      atomicAdd(&cntc[ei_c[EC + (i-EW)]], 1);
    else if (i < EW+EC+ER)   atomicAdd(&cntr[ei_r[ER + (i-EW-EC)]], 1);
}

// ---------------------------------------------------------------- 3 exclusive scans in one launch
__global__ __launch_bounds__(1024) void scan3_k(
    int* __restrict__ c0, int n0, int* __restrict__ o0,
    int* __restrict__ c1, int n1, int* __restrict__ o1,
    int* __restrict__ c2, int n2, int* __restrict__ o2)
{
    __shared__ int sa[1024], sb[1024];
    __shared__ int carry_s;
    int* cnt; int n; int* off;
    if (blockIdx.x == 0)      { cnt = c0; n = n0; off = o0; }
    else if (blockIdx.x == 1) { cnt = c1; n = n1; off = o1; }
    else                      { cnt = c2; n = n2; off = o2; }
    const int tid = threadIdx.x;
    if (tid == 0) carry_s = 0;
    __syncthreads();
    const int nchunk = (n + 1023) / 1024;
    for (int c = 0; c < nchunk; ++c) {
        int i = c*1024 + tid;
        int v = (i < n) ? cnt[i] : 0;
        sa[tid] = v;
        __syncthreads();
        int* s = sa; int* d = sb;
        for (int sh = 1; sh < 1024; sh <<= 1) {
            int t = s[tid] + ((tid >= sh) ? s[tid - sh] : 0);
            d[tid] = t;
            __syncthreads();
            int* tmp = s; s = d; d = tmp;
        }
        int inc = s[tid];
        int carry = carry_s;
        if (i < n) off[i] = carry + inc - v;
        __syncthreads();
        if (tid == 1023) carry_s = carry + inc;
        __syncthreads();
    }
    if (tid == 0) off[n] = carry_s;
}

// ---------------------------------------------------------------- adjacency fill (all 3; consumes cnt)
__global__ __launch_bounds__(256) void fill_all_k(
    const int* __restrict__ ei_w, const int* __restrict__ ei_c, const int* __restrict__ ei_r,
    const int* __restrict__ offw, const int* __restrict__ offc, const int* __restrict__ offr,
    int* __restrict__ cntw, int* __restrict__ cntc, int* __restrict__ cntr,
    int* __restrict__ adjw, int* __restrict__ adjc, int* __restrict__ adjr)
{
    int i = blockIdx.x * 256 + threadIdx.x;
    const int* ei; const int* off; int* cnt; int* adj; int e; int E;
    if (i < EW)            { e = i;        ei = ei_w; off = offw; cnt = cntw; adj = adjw; E = EW; }
    else if (i < EW+EC)    { e = i-EW;     ei = ei_c; off = offc; cnt = cntc; adj = adjc; E = EC; }
    else if (i < EW+EC+ER) { e = i-EW-EC;  ei = ei_r; off = offr; cnt = cntr; adj = adjr; E = ER; }
    else return;
    int d = ei[E + e];
    int p = atomicSub(&cnt[d], 1) - 1;
    adj[off[d] + p] = ei[e];
}

// ---------------------------------------------------------------- gather-mean D=128, all 3 relations
// one wave per dst node; lane holds float2; mean folded in
__global__ __launch_bounds__(256) void gather128_all_k(
    const float* __restrict__ x_paper, const float* __restrict__ x_author,
    const int* __restrict__ offw, const int* __restrict__ adjw, float* __restrict__ aggw,
    const int* __restrict__ offc, const int* __restrict__ adjc, float* __restrict__ aggc,
    const int* __restrict__ offr, const int* __restrict__ adjr, float* __restrict__ aggr)
{
    int W    = blockIdx.x * 4 + (threadIdx.x >> 6);
    int lane = threadIdx.x & 63;
    const float* X; const int* off; const int* adj; float* AGG; int w;
    if (W < NP)          { w = W;        X = x_author; off = offw; adj = adjw; AGG = aggw; }
    else if (W < 2*NP)   { w = W - NP;   X = x_paper;  off = offc; adj = adjc; AGG = aggc; }
    else if (W < 2*NP+NA){ w = W - 2*NP; X = x_paper;  off = offr; adj = adjr; AGG = aggr; }
    else return;
    int b = off[w], e = off[w+1];
    float2 acc = make_float2(0.f, 0.f);
    for (int j0 = b; j0 < e; j0 += 64) {
        int sl = (j0 + lane < e) ? adj[j0 + lane] : 0;
        int m  = min(64, e - j0);
        for (int k = 0; k < m; ++k) {
            int s = __shfl(sl, k, 64);
            float2 v = reinterpret_cast<const float2*>(X + (size_t)s * 128)[lane];
            acc.x += v.x; acc.y += v.y;
        }
    }
    float sc = 1.0f / fmaxf((float)(e - b), 1.0f);
    reinterpret_cast<float2*>(AGG + (size_t)w * 128)[lane] = make_float2(acc.x*sc, acc.y*sc);
}

// ---------------------------------------------------------------- fused multi-part GEMM, N=128
// C = relu?(alpha * sum_p(Ap @ Bp) + bias), Ap: M x 128, Bp: 128 x 128
// BM=128 BN=128 BK=32, 256 threads, 8x8 microtile (quadrant spread)
__device__ __forceinline__ void fma4(float4& c, float a, const float4& b) {
    c.x += a*b.x; c.y += a*b.y; c.z += a*b.z; c.w += a*b.w;
}

__global__ __launch_bounds__(256) void gemmf_k(
    const float* __restrict__ A0, const float* __restrict__ A1, const float* __restrict__ A2,
    const float* __restrict__ B0, const float* __restrict__ B1, const float* __restrict__ B2,
    float* __restrict__ C, int M, int nparts, float alpha,
    const float* __restrict__ bias, int relu)
{
    __shared__ float As[32][128];   // k-major (transposed)  16 KB
    __shared__ float Bs[32][128];   // k-major (natural)     16 KB
    const int tid  = threadIdx.x;
    const int row0 = blockIdx.x * 128;
    const int tx = tid & 15;        // col group: cols tx*4..+3 and 64+tx*4..+3
    const int ty = tid >> 4;        // row group: rows ty*4..+3 and 64+ty*4..+3

    float4 acc[2][2][4];
#pragma unroll
    for (int rh = 0; rh < 2; ++rh)
#pragma unroll
        for (int ch = 0; ch < 2; ++ch)
#pragma unroll
            for (int i = 0; i < 4; ++i) acc[rh][ch][i] = make_float4(0.f,0.f,0.f,0.f);

    const int KT = nparts * 4;
    for (int kt = 0; kt < KT; ++kt) {
        const int p  = kt >> 2;
        const int cb = (kt & 3) * 32;
        const float* Ap = (p == 0) ? A0 : (p == 1) ? A1 : A2;
        const float* Bp = (p == 0) ? B0 : (p == 1) ? B1 : B2;
        if (kt) __syncthreads();
        // stage A tile transposed: As[k][m]
#pragma unroll
        for (int i = 0; i < 4; ++i) {
            int idx = tid + i*256;          // 0..1023
            int m = idx & 127, kq = idx >> 7;
            int row = row0 + m;
            float4 v = make_float4(0.f,0.f,0.f,0.f);
            if (row < M) v = *reinterpret_cast<const float4*>(Ap + (size_t)row*128 + cb + kq*4);
            As[kq*4+0][m] = v.x; As[kq*4+1][m] = v.y;
            As[kq*4+2][m] = v.z; As[kq*4+3][m] = v.w;
        }
        // stage B tile: Bs[k][n]
#pragma unroll
        for (int i = 0; i < 4; ++i) {
            int idx = tid + i*256;
            int n4 = idx & 31, k = idx >> 5;
            *reinterpret_cast<float4*>(&Bs[k][n4*4]) =
                *reinterpret_cast<const float4*>(Bp + (size_t)(cb + k)*128 + n4*4);
        }
        __syncthreads();
#pragma unroll 8
        for (int k = 0; k < 32; ++k) {
            float4 a0 = *reinterpret_cast<const float4*>(&As[k][ty*4]);
            float4 a1 = *reinterpret_cast<const float4*>(&As[k][64 + ty*4]);
            float4 b0 = *reinterpret_cast<const float4*>(&Bs[k][tx*4]);
            float4 b1 = *reinterpret_cast<const float4*>(&Bs[k][64 + tx*4]);
#pragma unroll
            for (int i = 0; i < 4; ++i) {
                float av = (&a0.x)[i];
                fma4(acc[0][0][i], av, b0);
                fma4(acc[0][1][i], av, b1);
            }
#pragma unroll
            for (int i = 0; i < 4; ++i) {
                float av = (&a1.x)[i];
                fma4(acc[1][0][i], av, b0);
                fma4(acc[1][1][i], av, b1);
            }
        }
    }

#pragma unroll
    for (int rh = 0; rh < 2; ++rh)
#pragma unroll
        for (int i = 0; i < 4; ++i) {
            int row = row0 + rh*64 + ty*4 + i;
            if (row >= M) continue;
#pragma unroll
            for (int ch = 0; ch < 2; ++ch) {
                int col = ch*64 + tx*4;
                float4 t = acc[rh][ch][i];
                float4 bb = *reinterpret_cast<const float4*>(&bias[col]);
                t.x = alpha*t.x + bb.x; t.y = alpha*t.y + bb.y;
                t.z = alpha*t.z + bb.z; t.w = alpha*t.w + bb.w;
                if (relu) {
                    t.x = fmaxf(t.x, 0.f); t.y = fmaxf(t.y, 0.f);
                    t.z = fmaxf(t.z, 0.f); t.w = fmaxf(t.w, 0.f);
                }
                *reinterpret_cast<float4*>(C + (size_t)row*128 + col) = t;
            }
        }
}

// ---------------------------------------------------------------- GEMM K=128, N=40 (single B)
__global__ __launch_bounds__(256) void gemm40_k(
    const float* __restrict__ A, const float* __restrict__ B, float* __restrict__ C, int M)
{
    __shared__ float Bs[128][40];   // 20 KB
    __shared__ float As[24][128];   // 12 KB
    const int tid  = threadIdx.x;
    const int row0 = blockIdx.x * 24;

#pragma unroll
    for (int i = 0; i < 5; ++i) {
        int idx = tid + i*256;
        reinterpret_cast<float4*>(&Bs[0][0])[idx] = reinterpret_cast<const float4*>(B)[idx];
    }
#pragma unroll
    for (int i = 0; i < 3; ++i) {
        int idx = tid + i*256;
        int r = idx >> 5, c4 = idx & 31;
        int row = row0 + r;
        float4 v = make_float4(0.f,0.f,0.f,0.f);
        if (row < M) v = reinterpret_cast<const float4*>(A + (size_t)row*128)[c4];
        reinterpret_cast<float4*>(&As[r][0])[c4] = v;
    }
    __syncthreads();

    if (tid < 240) {
        int col  = tid % 40;
        int rsub = tid / 40;
        float a0=0.f, a1=0.f, a2=0.f, a3=0.f;
        for (int k = 0; k < 128; ++k) {
            float b = Bs[k][col];
            a0 += As[rsub*4+0][k]*b;
            a1 += As[rsub*4+1][k]*b;
            a2 += As[rsub*4+2][k]*b;
            a3 += As[rsub*4+3][k]*b;
        }
        int rb = row0 + rsub*4;
        if (rb+0 < M) C[(size_t)(rb+0)*40 + col] = a0;
        if (rb+1 < M) C[(size_t)(rb+1)*40 + col] = a1;
        if (rb+2 < M) C[(size_t)(rb+2)*40 + col] = a2;
        if (rb+3 < M) C[(size_t)(rb+3)*40 + col] = a3;
    }
}

// ---------------------------------------------------------------- dual-B GEMM K=128, N=40: reads A once
__global__ __launch_bounds__(256) void gemm40x2_k(
    const float* __restrict__ A, const float* __restrict__ B1, const float* __restrict__ B2,
    float* __restrict__ C1, float* __restrict__ C2, int M)
{
    __shared__ float Bs1[128][40];  // 20 KB
    __shared__ float Bs2[128][40];  // 20 KB
    __shared__ float As[24][128];   // 12 KB
    const int tid  = threadIdx.x;
    const int row0 = blockIdx.x * 24;

#pragma unroll
    for (int i = 0; i < 5; ++i) {
        int idx = tid + i*256;
        reinterpret_cast<float4*>(&Bs1[0][0])[idx] = reinterpret_cast<const float4*>(B1)[idx];
        reinterpret_cast<float4*>(&Bs2[0][0])[idx] = reinterpret_cast<const float4*>(B2)[idx];
    }
#pragma unroll
    for (int i = 0; i < 3; ++i) {
        int idx = tid + i*256;
        int r = idx >> 5, c4 = idx & 31;
        int row = row0 + r;
        float4 v = make_float4(0.f,0.f,0.f,0.f);
        if (row < M) v = reinterpret_cast<const float4*>(A + (size_t)row*128)[c4];
        reinterpret_cast<float4*>(&As[r][0])[c4] = v;
    }
    __syncthreads();

    if (tid < 240) {
        int col  = tid % 40;
        int rsub = tid / 40;
        float p0=0.f,p1=0.f,p2=0.f,p3=0.f;   // C1 accums
        float q0=0.f,q1=0.f,q2=0.f,q3=0.f;   // C2 accums
        for (int k = 0; k < 128; ++k) {
            float b1 = Bs1[k][col];
            float b2 = Bs2[k][col];
            float v0 = As[rsub*4+0][k], v1 = As[rsub*4+1][k];
            float v2 = As[rsub*4+2][k], v3 = As[rsub*4+3][k];
            p0 += v0*b1; p1 += v1*b1; p2 += v2*b1; p3 += v3*b1;
            q0 += v0*b2; q1 += v1*b2; q2 += v2*b2; q3 += v3*b2;
        }
        int rb = row0 + rsub*4;
        if (rb+0 < M) { C1[(size_t)(rb+0)*40 + col] = p0; C2[(size_t)(rb+0)*40 + col] = q0; }
        if (rb+1 < M) { C1[(size_t)(rb+1)*40 + col] = p1; C2[(size_t)(rb+1)*40 + col] = q1; }
        if (rb+2 < M) { C1[(size_t)(rb+2)*40 + col] = p2; C2[(size_t)(rb+2)*40 + col] = q2; }
        if (rb+3 < M) { C1[(size_t)(rb+3)*40 + col] = p3; C2[(size_t)(rb+3)*40 + col] = q3; }
    }
}

// ---------------------------------------------------------------- fused layer-1 gather + combine
// out[w] = 0.5*(mean_w(T1w) + mean_c(T1c) + out[w]) + b1p
__global__ __launch_bounds__(256) void gather40f_k(
    const float* __restrict__ T1w, const float* __restrict__ T1c,
    const int* __restrict__ offw, const int* __restrict__ adjw,
    const int* __restrict__ offc, const int* __restrict__ adjc,
    const float* __restrict__ b1p, float* __restrict__ out)
{
    int w    = blockIdx.x * 4 + (threadIdx.x >> 6);
    int lane = threadIdx.x & 63;
    if (w >= NP) return;
    const bool act = lane < 40;

    float aw = 0.f;
    {
        int b = offw[w], e = offw[w+1];
        for (int j0 = b; j0 < e; j0 += 64) {
            int sl = (j0 + lane < e) ? adjw[j0 + lane] : 0;
            int m  = min(64, e - j0);
            for (int k = 0; k < m; ++k) {
                int s = __shfl(sl, k, 64);
                if (act) aw += T1w[(size_t)s * 40 + lane];
            }
        }
        aw *= 1.0f / fmaxf((float)(e - b), 1.0f);
    }
    float ac = 0.f;
    {
        int b = offc[w], e = offc[w+1];
        for (int j0 = b; j0 < e; j0 += 64) {
            int sl = (j0 + lane < e) ? adjc[j0 + lane] : 0;
            int m  = min(64, e - j0);
            for (int k = 0; k < m; ++k) {
                int s = __shfl(sl, k, 64);
                if (act) ac += T1c[(size_t)s * 40 + lane];
            }
        }
        ac *= 1.0f / fmaxf((float)(e - b), 1.0f);
    }
    if (act) {
        size_t idx = (size_t)w * 40 + lane;
        out[idx] = 0.5f*(aw + ac + out[idx]) + b1p[lane];
    }
}

// ---------------------------------------------------------------- launch
extern "C" void kernel_launch(void* const* d_in, const int* in_sizes, int n_in,
                              void* d_out, int out_size, void* d_ws, size_t ws_size,
                              hipStream_t stream)
{
    (void)in_sizes; (void)n_in; (void)out_size; (void)ws_size;

    const float* x_paper  = (const float*)d_in[0];
    const float* x_author = (const float*)d_in[1];
    const int*   ei_w     = (const int*)d_in[2];
    const int*   ei_c     = (const int*)d_in[3];
    const int*   ei_r     = (const int*)d_in[4];
    const float* Wl0w = (const float*)d_in[5];
    const float* bl0w = (const float*)d_in[6];
    const float* Wr0w = (const float*)d_in[7];
    const float* Wl0c = (const float*)d_in[8];
    const float* bl0c = (const float*)d_in[9];
    const float* Wr0c = (const float*)d_in[10];
    const float* Wl0r = (const float*)d_in[11];
    const float* bl0r = (const float*)d_in[12];
    const float* Wr0r = (const float*)d_in[13];
    const float* Wl1w = (const float*)d_in[14];
    const float* bl1w = (const float*)d_in[15];
    const float* Wr1w = (const float*)d_in[16];
    const float* Wl1c = (const float*)d_in[17];
    const float* bl1c = (const float*)d_in[18];
    const float* Wr1c = (const float*)d_in[19];
    // d_in[20..22] = Wl1_r / bl1_r / Wr1_r: dead (layer-1 author output unused)
    float* out = (float*)d_out;

    float* ws = (float*)d_ws;
    size_t o = 0;
    int* cntw = (int*)(ws + o); o += NP;
    int* cntc = (int*)(ws + o); o += NP;
    int* cntr = (int*)(ws + o); o += NA;
    const size_t zeroInts = o;               // memset region (cnt/cursor)
    int* offw = (int*)(ws + o); o += NP + 1;
    int* offc = (int*)(ws + o); o += NP + 1;
    int* offr = (int*)(ws + o); o += NA + 1;
    o = (o + 3) & ~(size_t)3;                // 16B-align
    int* adjw = (int*)(ws + o); o += EW;
    int* adjc = (int*)(ws + o); o += EC;
    int* adjr = (int*)(ws + o); o += ER;
    float* aggw = ws + o; o += (size_t)NP*128;
    float* aggc = ws + o; o += (size_t)NP*128;
    float* aggr = ws + o; o += (size_t)NA*128;
    float* hp1  = ws + o; o += (size_t)NP*128;
    float* ha1  = ws + o; o += (size_t)NA*128;
    float* Wr0wc = ws + o; o += 128*128;
    float* b0p   = ws + o; o += 128;
    float* Wr1wc = ws + o; o += 128*40;
    float* b1p   = ws + o; o += 40;
    // aliases (aggw free after paper gemmf)
    float* T1w   = aggw;                 // NA*40
    float* T1c   = aggw + (size_t)NA*40; // NP*40  (2.8M floats <= NP*128)

    hipMemsetAsync(d_ws, 0, zeroInts * sizeof(int), stream);

    prep_k<<<64, 256, 0, stream>>>(Wr0w, Wr0c, bl0w, bl0c, Wr1w, Wr1c, bl1w, bl1c,
                                   Wr0wc, b0p, Wr1wc, b1p);

    // CSR build (per call; ws is re-poisoned between calls)
    count_all_k<<<(EW+EC+ER+255)/256, 256, 0, stream>>>(ei_w, ei_c, ei_r, cntw, cntc, cntr);
    scan3_k<<<3, 1024, 0, stream>>>(cntw, NP, offw, cntc, NP, offc, cntr, NA, offr);
    fill_all_k<<<(EW+EC+ER+255)/256, 256, 0, stream>>>(ei_w, ei_c, ei_r, offw, offc, offr,
                                                       cntw, cntc, cntr, adjw, adjc, adjr);

    // layer 0: gather-mean of raw features (D=128), all 3 relations, mean folded in
    gather128_all_k<<<(2*NP+NA+3)/4, 256, 0, stream>>>(x_paper, x_author,
                                                       offw, adjw, aggw,
                                                       offc, adjc, aggc,
                                                       offr, adjr, aggr);

    // hp1 = relu(0.5*(xp@Wr0wc + mw@Wl0w + mc@Wl0c) + b0p)   [K=384 fused]
    gemmf_k<<<(NP+127)/128, 256, 0, stream>>>(x_paper, aggw, aggc, Wr0wc, Wl0w, Wl0c,
                                              hp1, NP, 3, 0.5f, b0p, 1);
    // ha1 = relu(xa@Wr0r + mr@Wl0r + bl0r)                    [K=256 fused]
    gemmf_k<<<(NA+127)/128, 256, 0, stream>>>(x_author, aggr, nullptr, Wr0r, Wl0r, nullptr,
                                              ha1, NA, 2, 1.0f, bl0r, 1);

    // layer 1: transform first (40 dims), then gather
    gemm40_k  <<<(NA+23)/24, 256, 0, stream>>>(ha1, Wl1w, T1w, NA);
    gemm40x2_k<<<(NP+23)/24, 256, 0, stream>>>(hp1, Wl1c, Wr1wc, T1c, out, NP);

    // fused: out = 0.5*(mean_w(T1w) + mean_c(T1c) + out) + b1p
    gather40f_k<<<(NP+3)/4, 256, 0, stream>>>(T1w, T1c, offw, adjw, offc, adjc, b1p, out);
}